// Round 4
// baseline (13360.611 us; speedup 1.0000x reference)
//
#include <hip/hip_runtime.h>

typedef unsigned short u16;
typedef unsigned int u32;
typedef unsigned long long u64;
typedef __attribute__((ext_vector_type(8))) short short8;
typedef __attribute__((ext_vector_type(4))) float f4;
typedef __attribute__((ext_vector_type(4))) unsigned short us4;

#define MFMA_BF16(a, b, c) __builtin_amdgcn_mfma_f32_16x16x32_bf16((a), (b), (c), 0, 0, 0)

#define Bsz 64
#define Ssz 1024
#define Isz 512
#define Hsz 512
#define G4  2048      // 4*H packed gate rows
#define SCH 128       // timesteps per chunk
#define NCHUNK 8
#define SCAN_NB 64    // scan grid (<= 256 CUs -> co-resident)

// ---- workspace layout (bytes). total ~68.4 MB ----
#define WS_EPOCH 0           // 4        run epoch (device-side bump per replay)
#define WS_BIAS  4096        // 2048*4   combined bias, packed order
#define WS_HBUF  16384       // 2*32768*4  h double buffer, TAGGED u32 [slot][b][j]
#define WS_CBUF  278528      // 32768*4    c state fp32 [b][j]
#define WS_WI    409600      // 2048*512*2 Wi bf16 packed [row'][k]
#define WS_WH    2506752     // 2048*512*2 Wh bf16 packed [row'][k]
#define WS_XC    4603904     // 64*128*2048*4  x_proj chunk fp32 [b][s_local][row']

#define HF_OFF ((size_t)Bsz * Ssz * Hsz)           // 33554432
#define CF_OFF (HF_OFF + (size_t)Bsz * Hsz)

__device__ __forceinline__ u16 bf16rne(float f) {
    unsigned int x = __float_as_uint(f);
    unsigned int r = (x + 0x7fffu + ((x >> 16) & 1u)) >> 16;
    return (u16)r;
}
__device__ __forceinline__ float sigf(float x) { return 1.0f / (1.0f + __expf(-x)); }
__device__ __forceinline__ float tanh_(float x) { return 1.0f - 2.0f / (__expf(2.0f * x) + 1.0f); }

// ------------------------------------------------------------------
// epoch bump: runs once per graph replay, before prep. Gives each run
// a distinct tag base so stale tagged h from a previous run can never
// satisfy this run's polls (every slot is rewritten every run, so the
// 16-bit wrap at 32 epochs is unreachable by stale data).
// ------------------------------------------------------------------
__global__ void epoch_bump(u32* e) {
    u32 v = __hip_atomic_load(e, __ATOMIC_RELAXED, __HIP_MEMORY_SCOPE_AGENT);
    __hip_atomic_store(e, v + 1u, __ATOMIC_RELAXED, __HIP_MEMORY_SCOPE_AGENT);
}

// ------------------------------------------------------------------
// prep: pack weights (bf16, gate-interleaved rows), combine biases,
// init tagged h0 (slot 1) and c state.
// ------------------------------------------------------------------
struct PrepArgs {
    const float* h0; const float* c0;
    const float* wi[4]; const float* wh[4];
    const float* bi[4]; const float* bh[4];   // bh order fixed to (i,f,g,o) by host
    u16* Wi; u16* Wh; float* bias; u32* hbuf; float* cbuf; const u32* epoch;
};
#define PREP_TOT (1048576 + 1048576 + 2048 + 32768 + 32768)

__global__ void lstm_prep(PrepArgs a) {
    long i = (long)blockIdx.x * 256 + threadIdx.x;
    if (i < 1048576) {                       // Wi pack
        int rowp = (int)(i >> 9), k = (int)(i & 511);
        int unit = rowp >> 2, gate = rowp & 3;
        a.Wi[i] = bf16rne(a.wi[gate][unit * Isz + k]);
    } else if (i < 2097152) {                // Wh pack
        long j = i - 1048576;
        int rowp = (int)(j >> 9), k = (int)(j & 511);
        int unit = rowp >> 2, gate = rowp & 3;
        a.Wh[j] = bf16rne(a.wh[gate][unit * Hsz + k]);
    } else if (i < 2097152 + 2048) {         // bias combine (packed order)
        int j = (int)(i - 2097152);
        int unit = j >> 2, gate = j & 3;
        a.bias[j] = a.bi[gate][unit] + a.bh[gate][unit];
    } else if (i < 2097152 + 2048 + 32768) { // h0 -> tagged slot 1 (tag = ebase-1)
        int j = (int)(i - (2097152 + 2048));
        u32 ep = __hip_atomic_load(a.epoch, __ATOMIC_RELAXED, __HIP_MEMORY_SCOPE_AGENT);
        u32 tg = ((ep * 2048u - 1u) & 0xffffu) << 16;
        __hip_atomic_store(&a.hbuf[32768 + j], tg | (u32)bf16rne(a.h0[j]),
                           __ATOMIC_RELAXED, __HIP_MEMORY_SCOPE_AGENT);
    } else if (i < PREP_TOT) {               // c0 -> c state
        int j = (int)(i - (2097152 + 2048 + 32768));
        a.cbuf[j] = a.c0[j];
    }
}

// ------------------------------------------------------------------
// x_proj GEMM: one chunk of 128 timesteps.
// ------------------------------------------------------------------
__global__ __launch_bounds__(256) void xproj_gemm(
    const float* __restrict__ inp, const u16* __restrict__ Wi,
    float* __restrict__ xc, int t0)
{
    __shared__ u16 Al[128 * 40];   // [m][k] pad 32->40
    __shared__ u16 Bl[128 * 40];   // [n][k]
    const int tid = threadIdx.x;
    const int L = tid & 63, w = tid >> 6;
    const int q = L >> 4, lm = L & 15;
    const int nt = blockIdx.x & 15, b = blockIdx.x >> 4;
    const float* Abase = inp + ((size_t)b * Ssz + t0) * Isz;
    const u16* Bbase = Wi + (size_t)nt * 128 * Isz;
    const int mh = (w & 1) * 64, nh = (w >> 1) * 64;

    f4 acc[4][4];
#pragma unroll
    for (int i = 0; i < 4; ++i)
#pragma unroll
        for (int j = 0; j < 4; ++j) acc[i][j] = (f4){0.f, 0.f, 0.f, 0.f};

    for (int kt = 0; kt < 16; ++kt) {
        const int k0 = kt * 32;
#pragma unroll
        for (int r = 0; r < 4; ++r) {
            int flat = tid + r * 256;
            int m = flat >> 3, kq = flat & 7;
            f4 v = *(const f4*)(Abase + (size_t)m * Isz + k0 + kq * 4);
            us4 h = {bf16rne(v.x), bf16rne(v.y), bf16rne(v.z), bf16rne(v.w)};
            *(us4*)(&Al[m * 40 + kq * 4]) = h;
        }
#pragma unroll
        for (int r = 0; r < 2; ++r) {
            int flat = tid + r * 256;
            int n = flat >> 2, kq = flat & 3;
            *(short8*)(&Bl[n * 40 + kq * 8]) =
                *(const short8*)(Bbase + (size_t)n * Isz + k0 + kq * 8);
        }
        __syncthreads();
        short8 af[4], bfr[4];
#pragma unroll
        for (int i = 0; i < 4; ++i)
            af[i] = *(const short8*)(&Al[(mh + i * 16 + lm) * 40 + q * 8]);
#pragma unroll
        for (int j = 0; j < 4; ++j)
            bfr[j] = *(const short8*)(&Bl[(nh + j * 16 + lm) * 40 + q * 8]);
#pragma unroll
        for (int i = 0; i < 4; ++i)
#pragma unroll
            for (int j = 0; j < 4; ++j)
                acc[i][j] = MFMA_BF16(af[i], bfr[j], acc[i][j]);
        __syncthreads();
    }
    float* Obase = xc + (size_t)b * SCH * G4 + (size_t)nt * 128;
#pragma unroll
    for (int i = 0; i < 4; ++i)
#pragma unroll
        for (int j = 0; j < 4; ++j)
#pragma unroll
            for (int r = 0; r < 4; ++r) {
                int m = mh + i * 16 + q * 4 + r;   // s_local
                int n = nh + j * 16 + lm;
                Obase[(size_t)m * G4 + n] = acc[i][j][r];
            }
}

// ------------------------------------------------------------------
// persistent scan, tagged-data protocol ("the data IS the flag").
// h is published as tagged u32 per unit: (tag16 << 16) | bf16(h).
// tag16 = (epoch*2048 + t) & 0xffff. Publisher: one fire-and-forget
// 8-B agent-scope store per thread (two tagged units) -- NO vmcnt
// drain, NO separate flag, NO trailing barrier. Consumer: the h
// gather IS the poll -- load 64 u64 atoms (sc1, served by MALL),
// check every tag, retry until all fresh. The successful iteration
// leaves the data in registers.
// Happens-before matches the old flag protocol: a block reaches step
// t+1 only after observing EVERY unit of h(t); each block's h(t)
// publish is after its per-step barrier, which all its waves reach
// only after all passed their polls of h(t-1). So h(t+1) stores can
// never land while any wave still needs tag t-1 -> no deadlock, and
// slot parity (2 slots) suffices. Tag mismatch just spins.
// One barrier per step (gate_buf exchange), double-buffered on t&1.
// ------------------------------------------------------------------
__global__ __launch_bounds__(256, 1) void lstm_scan(
    const float* __restrict__ xc, const u16* __restrict__ Whp,
    const float* __restrict__ bias, u32* __restrict__ hbuf,
    float* __restrict__ cbuf, const u32* __restrict__ epoch_p,
    float* __restrict__ out, int t0)
{
    __shared__ float gate_buf[2][64 * 32];   // [t&1][b][n_local]
    const int tid = threadIdx.x, bid = blockIdx.x;
    const int L = tid & 63, w = tid >> 6;
    const int q = L >> 4, lm = L & 15;
    const int row0 = bid * 32;   // packed gate rows owned
    const int j0 = bid * 8;      // hidden units owned
    const int myb = w * 16 + lm; // batch row for A fragment

    const u32 ebase = __hip_atomic_load(epoch_p, __ATOMIC_RELAXED,
                                        __HIP_MEMORY_SCOPE_AGENT) * 2048u;

    // loop-invariant B fragments (weights); compiler may keep or reload from L2
    short8 wb[16][2];
#pragma unroll
    for (int kt = 0; kt < 16; ++kt)
#pragma unroll
        for (int jt = 0; jt < 2; ++jt) {
            int n = row0 + jt * 16 + lm;
            wb[kt][jt] = *(const short8*)(Whp + (size_t)n * Hsz + kt * 32 + q * 8);
        }

    const int be = tid >> 2;
    const int u0 = (tid & 3) * 2;
    const f4 bias0 = *(const f4*)(bias + row0 + u0 * 4);
    const f4 bias1 = *(const f4*)(bias + row0 + u0 * 4 + 4);
    float c0r = cbuf[be * Hsz + j0 + u0];
    float c1r = cbuf[be * Hsz + j0 + u0 + 1];

    for (int t = t0; t < t0 + SCH; ++t) {
        const int sl = t - t0;
        // x prefetch (independent of h -> in flight across the poll)
        const float* xrow = xc + ((size_t)be * SCH + sl) * G4 + row0 + u0 * 4;
        f4 xv0 = *(const f4*)(xrow);
        f4 xv1 = *(const f4*)(xrow + 4);

        // ---- tagged gather of h(t-1) from slot (t&1)^1: poll == gather ----
        // fused load+check+pack per 8B keeps register pressure low (no
        // 64-u64 raw[] array live across the loop -> no scratch spill in
        // the spin loop).
        const u32 texp = ((ebase + (u32)(t - 1)) & 0xffffu) << 16;
        const u64* hq = (const u64*)(hbuf + (size_t)((t & 1) ^ 1) * 32768)
                        + (size_t)myb * 256;
        union AU { u32 u[4]; short8 v; } au[16];
        for (;;) {
            u32 bad = 0;
#pragma unroll
            for (int kt = 0; kt < 16; ++kt)
#pragma unroll
                for (int m = 0; m < 4; ++m) {
                    u64 r = __hip_atomic_load(hq + kt * 16 + q * 4 + m,
                                              __ATOMIC_RELAXED,
                                              __HIP_MEMORY_SCOPE_AGENT);
                    u32 lo = (u32)r;
                    u32 hi = (u32)(r >> 32);
                    bad |= ((lo ^ texp) | (hi ^ texp)) & 0xffff0000u;
                    au[kt].u[m] = (lo & 0xffffu) | (hi << 16);
                }
            if (__all(bad == 0)) break;
            __builtin_amdgcn_s_sleep(1);   // backoff: don't hammer the MALL
        }

        f4 acc0 = (f4){0.f, 0.f, 0.f, 0.f}, acc1 = acc0;
#pragma unroll
        for (int kt = 0; kt < 16; ++kt) {
            acc0 = MFMA_BF16(au[kt].v, wb[kt][0], acc0);
            acc1 = MFMA_BF16(au[kt].v, wb[kt][1], acc1);
        }

        float* gb = gate_buf[t & 1];
#pragma unroll
        for (int r = 0; r < 4; ++r) {
            int brow = w * 16 + q * 4 + r;
            gb[brow * 32 + lm] = acc0[r];
            gb[brow * 32 + 16 + lm] = acc1[r];
        }
        __syncthreads();   // only barrier per step (gate_buf parity-protected)

        f4 g0 = *(const f4*)(&gb[be * 32 + u0 * 4]);
        f4 g1 = *(const f4*)(&gb[be * 32 + u0 * 4 + 4]);
        g0 += xv0 + bias0;
        g1 += xv1 + bias1;
        float i1 = sigf(g0.x), f1 = sigf(g0.y), gg1 = tanh_(g0.z), o1 = sigf(g0.w);
        c0r = f1 * c0r + i1 * gg1;
        float h1 = o1 * tanh_(c0r);
        float i2 = sigf(g1.x), fg2 = sigf(g1.y), gg2 = tanh_(g1.z), o2 = sigf(g1.w);
        c1r = fg2 * c1r + i2 * gg2;
        float h2 = o2 * tanh_(c1r);

        // h(t) publish: one tagged 8-B store, fire and forget.
        u32 tg = ((ebase + (u32)t) & 0xffffu) << 16;
        u64 hv = (u64)(tg | (u32)bf16rne(h1))
               | ((u64)(tg | (u32)bf16rne(h2)) << 32);
        u64* hw = (u64*)(hbuf + (size_t)(t & 1) * 32768 + be * Hsz + j0 + u0);
        __hip_atomic_store(hw, hv, __ATOMIC_RELAXED, __HIP_MEMORY_SCOPE_AGENT);

        float* op = out + ((size_t)be * Ssz + t) * Hsz + j0 + u0;
        op[0] = h1;
        op[1] = h2;
        if (t == Ssz - 1) {
            out[HF_OFF + be * Hsz + j0 + u0] = h1;
            out[HF_OFF + be * Hsz + j0 + u0 + 1] = h2;
            out[CF_OFF + be * Hsz + j0 + u0] = c0r;
            out[CF_OFF + be * Hsz + j0 + u0 + 1] = c1r;
        }
    }
    cbuf[be * Hsz + j0 + u0] = c0r;
    cbuf[be * Hsz + j0 + u0 + 1] = c1r;
}

// ------------------------------------------------------------------
extern "C" void kernel_launch(void* const* d_in, const int* in_sizes, int n_in,
                              void* d_out, int out_size, void* d_ws, size_t ws_size,
                              hipStream_t stream) {
    const float* inputs = (const float*)d_in[0];
    char* W = (char*)d_ws;
    u32*  epoch = (u32*)(W + WS_EPOCH);
    float* bias = (float*)(W + WS_BIAS);
    u32*  hbuf = (u32*)(W + WS_HBUF);
    float* cbuf = (float*)(W + WS_CBUF);
    u16*  Wi   = (u16*)(W + WS_WI);
    u16*  Wh   = (u16*)(W + WS_WH);
    float* xch  = (float*)(W + WS_XC);

    PrepArgs a;
    a.h0 = (const float*)d_in[1];
    a.c0 = (const float*)d_in[2];
    for (int g = 0; g < 4; ++g) {
        a.wi[g] = (const float*)d_in[3 + g];
        a.wh[g] = (const float*)d_in[7 + g];
        a.bi[g] = (const float*)d_in[11 + g];
    }
    // dict order at the tail is b_hi, b_hf, b_ho, b_hg -> remap to (i,f,g,o)
    a.bh[0] = (const float*)d_in[15];
    a.bh[1] = (const float*)d_in[16];
    a.bh[2] = (const float*)d_in[18];
    a.bh[3] = (const float*)d_in[17];
    a.Wi = Wi; a.Wh = Wh; a.bias = bias; a.hbuf = hbuf; a.cbuf = cbuf; a.epoch = epoch;

    epoch_bump<<<1, 1, 0, stream>>>(epoch);
    lstm_prep<<<(PREP_TOT + 255) / 256, 256, 0, stream>>>(a);

    float* out = (float*)d_out;
    for (int c = 0; c < NCHUNK; ++c) {
        int t0 = c * SCH;
        xproj_gemm<<<dim3(64 * 16), 256, 0, stream>>>(inputs, Wi, xch, t0);
        lstm_scan<<<dim3(SCAN_NB), 256, 0, stream>>>(xch, Wh, bias, hbuf, cbuf, epoch, out, t0);
    }
}

// Round 5
// 7942.290 us; speedup vs baseline: 1.6822x; 1.6822x over previous
//
#include <hip/hip_runtime.h>

typedef unsigned short u16;
typedef unsigned int u32;
typedef unsigned long long u64;
typedef __attribute__((ext_vector_type(8))) short short8;
typedef __attribute__((ext_vector_type(4))) float f4;
typedef __attribute__((ext_vector_type(4))) unsigned short us4;

#define MFMA_BF16(a, b, c) __builtin_amdgcn_mfma_f32_16x16x32_bf16((a), (b), (c), 0, 0, 0)

#define Bsz 64
#define Ssz 1024
#define Isz 512
#define Hsz 512
#define G4  2048      // 4*H packed gate rows
#define SCH 128       // timesteps per chunk
#define NCHUNK 8
#define SCAN_NB 64    // scan grid (<= 256 CUs -> co-resident)

// ---- workspace layout (bytes). total ~69.3 MB ----
#define WS_FLAG  0           // 1024*256*4  per-(step,block,wave) flags
#define WS_BIAS  1048576     // 2048*4
#define WS_HBUF  1056768     // 2*32768*2   h double buffer, bf16 [slot][b][j]
#define WS_CBUF  1187840     // 32768*4
#define WS_WI    1318912     // 2048*512*2
#define WS_WH    3416064     // 2048*512*2
#define WS_XC    5513216     // 64*128*2048*4

#define HF_OFF ((size_t)Bsz * Ssz * Hsz)           // 33554432
#define CF_OFF (HF_OFF + (size_t)Bsz * Hsz)

__device__ __forceinline__ u16 bf16rne(float f) {
    unsigned int x = __float_as_uint(f);
    unsigned int r = (x + 0x7fffu + ((x >> 16) & 1u)) >> 16;
    return (u16)r;
}
__device__ __forceinline__ float sigf(float x) { return 1.0f / (1.0f + __expf(-x)); }
__device__ __forceinline__ float tanh_(float x) { return 1.0f - 2.0f / (__expf(2.0f * x) + 1.0f); }

// ------------------------------------------------------------------
// prep: pack weights, combine biases, init h0 (bf16, slot 1) and c,
// zero the per-(step,block,wave) flag array.
// ------------------------------------------------------------------
struct PrepArgs {
    const float* h0; const float* c0;
    const float* wi[4]; const float* wh[4];
    const float* bi[4]; const float* bh[4];   // bh order fixed to (i,f,g,o) by host
    u16* Wi; u16* Wh; float* bias; u16* hbuf; float* cbuf; int* flag;
};
#define PREP_TOT (1048576 + 1048576 + 2048 + 32768 + 32768 + 262144)

__global__ void lstm_prep(PrepArgs a) {
    long i = (long)blockIdx.x * 256 + threadIdx.x;
    if (i < 1048576) {                       // Wi pack
        int rowp = (int)(i >> 9), k = (int)(i & 511);
        int unit = rowp >> 2, gate = rowp & 3;
        a.Wi[i] = bf16rne(a.wi[gate][unit * Isz + k]);
    } else if (i < 2097152) {                // Wh pack
        long j = i - 1048576;
        int rowp = (int)(j >> 9), k = (int)(j & 511);
        int unit = rowp >> 2, gate = rowp & 3;
        a.Wh[j] = bf16rne(a.wh[gate][unit * Hsz + k]);
    } else if (i < 2097152 + 2048) {         // bias combine (packed order)
        int j = (int)(i - 2097152);
        int unit = j >> 2, gate = j & 3;
        a.bias[j] = a.bi[gate][unit] + a.bh[gate][unit];
    } else if (i < 2097152 + 2048 + 32768) { // h0 -> bf16 slot 1
        int j = (int)(i - (2097152 + 2048));
        a.hbuf[32768 + j] = bf16rne(a.h0[j]);
    } else if (i < 2097152 + 2048 + 65536) { // c0 -> c state
        int j = (int)(i - (2097152 + 2048 + 32768));
        a.cbuf[j] = a.c0[j];
    } else if (i < PREP_TOT) {               // zero flags (kernel boundary flushes)
        a.flag[i - (2097152 + 2048 + 65536)] = 0;
    }
}

// ------------------------------------------------------------------
// x_proj GEMM: one chunk of 128 timesteps.
// ------------------------------------------------------------------
__global__ __launch_bounds__(256) void xproj_gemm(
    const float* __restrict__ inp, const u16* __restrict__ Wi,
    float* __restrict__ xc, int t0)
{
    __shared__ u16 Al[128 * 40];   // [m][k] pad 32->40
    __shared__ u16 Bl[128 * 40];   // [n][k]
    const int tid = threadIdx.x;
    const int L = tid & 63, w = tid >> 6;
    const int q = L >> 4, lm = L & 15;
    const int nt = blockIdx.x & 15, b = blockIdx.x >> 4;
    const float* Abase = inp + ((size_t)b * Ssz + t0) * Isz;
    const u16* Bbase = Wi + (size_t)nt * 128 * Isz;
    const int mh = (w & 1) * 64, nh = (w >> 1) * 64;

    f4 acc[4][4];
#pragma unroll
    for (int i = 0; i < 4; ++i)
#pragma unroll
        for (int j = 0; j < 4; ++j) acc[i][j] = (f4){0.f, 0.f, 0.f, 0.f};

    for (int kt = 0; kt < 16; ++kt) {
        const int k0 = kt * 32;
#pragma unroll
        for (int r = 0; r < 4; ++r) {
            int flat = tid + r * 256;
            int m = flat >> 3, kq = flat & 7;
            f4 v = *(const f4*)(Abase + (size_t)m * Isz + k0 + kq * 4);
            us4 h = {bf16rne(v.x), bf16rne(v.y), bf16rne(v.z), bf16rne(v.w)};
            *(us4*)(&Al[m * 40 + kq * 4]) = h;
        }
#pragma unroll
        for (int r = 0; r < 2; ++r) {
            int flat = tid + r * 256;
            int n = flat >> 2, kq = flat & 3;
            *(short8*)(&Bl[n * 40 + kq * 8]) =
                *(const short8*)(Bbase + (size_t)n * Isz + k0 + kq * 8);
        }
        __syncthreads();
        short8 af[4], bfr[4];
#pragma unroll
        for (int i = 0; i < 4; ++i)
            af[i] = *(const short8*)(&Al[(mh + i * 16 + lm) * 40 + q * 8]);
#pragma unroll
        for (int j = 0; j < 4; ++j)
            bfr[j] = *(const short8*)(&Bl[(nh + j * 16 + lm) * 40 + q * 8]);
#pragma unroll
        for (int i = 0; i < 4; ++i)
#pragma unroll
            for (int j = 0; j < 4; ++j)
                acc[i][j] = MFMA_BF16(af[i], bfr[j], acc[i][j]);
        __syncthreads();
    }
    float* Obase = xc + (size_t)b * SCH * G4 + (size_t)nt * 128;
#pragma unroll
    for (int i = 0; i < 4; ++i)
#pragma unroll
        for (int j = 0; j < 4; ++j)
#pragma unroll
            for (int r = 0; r < 4; ++r) {
                int m = mh + i * 16 + q * 4 + r;   // s_local
                int n = nh + j * 16 + lm;
                Obase[(size_t)m * G4 + n] = acc[i][j][r];
            }
}

// ------------------------------------------------------------------
// persistent scan, WAVE-AUTONOMOUS flag protocol.
// Decomposition: wave w of block bid owns (batches 16w..16w+15) x
// (units bid*8..bid*8+7). Its gather needs batches 16w..16w+15 of ALL
// units -> produced exactly by wave w of every block. The gate_buf
// transpose is also intra-wave (write rows w*16..w*16+15, read rows
// tid>>2 in the same range). So the 4 waves form 4 INDEPENDENT sync
// planes: ZERO __syncthreads in the step loop.
// Per step, per wave: poll 64 per-wave flags (1 dword/lane) -> gather
// h(t-1) (32 x 8B agent loads) -> 32 MFMA (B from LDS-staged Wh) ->
// intra-wave LDS transpose -> gates -> publish h -> wave-local
// s_waitcnt vmcnt(0) -> flag store. Slot-parity safety per plane: a
// wave publishes t+1 only after polling all plane flags of t, which
// implies every plane wave finished its t-gather of h(t-1) (gather
// precedes publish in program order) -> 2 slots suffice.
// Wh slice staged in LDS once: kills the per-step L2 weight reloads
// (old VGPR=100 proved wb[16][2] was never register-resident).
// ------------------------------------------------------------------
__global__ __launch_bounds__(256, 1) void lstm_scan(
    const float* __restrict__ xc, const u16* __restrict__ Whp,
    const float* __restrict__ bias, u16* __restrict__ hbuf,
    float* __restrict__ cbuf, int* __restrict__ flag,
    float* __restrict__ out, int t0)
{
    __shared__ u16 whl[16384];       // Wh slice, fragment-ordered: 32 KB
    __shared__ float gb[64 * 36];    // transpose buf, stride 36 (16B-aligned, low-conflict)
    const int tid = threadIdx.x, bid = blockIdx.x;
    const int L = tid & 63, w = tid >> 6;
    const int q = L >> 4, lm = L & 15;
    const int row0 = bid * 32;   // packed gate rows owned
    const int j0 = bid * 8;      // hidden units owned
    const int myb = w * 16 + lm; // batch row for A fragment

    // ---- stage Wh slice into LDS in MFMA fragment order ----
    // fragment f = ((jt*16+kt)*16+lm)*4+q lives at whl[f*8], holds
    // B[row0+jt*16+lm][kt*32+q*8 .. +8]
#pragma unroll
    for (int i = 0; i < 8; ++i) {
        int f = tid + i * 256;
        int qq = f & 3, lmm = (f >> 2) & 15, ktt = (f >> 6) & 15, jtt = f >> 10;
        *(short8*)(&whl[f * 8]) =
            *(const short8*)(Whp + (size_t)(row0 + jtt * 16 + lmm) * Hsz
                             + ktt * 32 + qq * 8);
    }

    const int be = tid >> 2;         // batch row this thread's gates belong to
    const int u0 = (tid & 3) * 2;    // first of 2 hidden units
    const f4 bias0 = *(const f4*)(bias + row0 + u0 * 4);
    const f4 bias1 = *(const f4*)(bias + row0 + u0 * 4 + 4);
    float c0r = cbuf[be * Hsz + j0 + u0];
    float c1r = cbuf[be * Hsz + j0 + u0 + 1];

    __syncthreads();   // whl staged; the ONLY barrier in this kernel

    for (int t = t0; t < t0 + SCH; ++t) {
        const int sl = t - t0;
        // x prefetch (independent of h -> in flight across the poll)
        const float* xrow = xc + ((size_t)be * SCH + sl) * G4 + row0 + u0 * 4;
        f4 xv0 = *(const f4*)(xrow);
        f4 xv1 = *(const f4*)(xrow + 4);

        // ---- per-plane poll: lane l checks block l's wave-w flag ----
        if (t > 0) {
            const int* fl = flag + (size_t)(t - 1) * 256 + w * 64;
            int v;
            do {
                v = __hip_atomic_load(&fl[L], __ATOMIC_RELAXED,
                                      __HIP_MEMORY_SCOPE_AGENT);
                if (__all(v)) break;
                __builtin_amdgcn_s_sleep(1);
            } while (1);
        }

        // ---- h(t-1) gather, device-coherent 8B loads (once, no retry) ----
        const u64* hq = (const u64*)(hbuf + (size_t)((t & 1) ^ 1) * 32768)
                        + (size_t)myb * 128;
        union { short8 v; u64 q2[2]; } au[16];
#pragma unroll
        for (int kt = 0; kt < 16; ++kt) {
            au[kt].q2[0] = __hip_atomic_load(hq + kt * 8 + q * 2,
                                             __ATOMIC_RELAXED, __HIP_MEMORY_SCOPE_AGENT);
            au[kt].q2[1] = __hip_atomic_load(hq + kt * 8 + q * 2 + 1,
                                             __ATOMIC_RELAXED, __HIP_MEMORY_SCOPE_AGENT);
        }

        // ---- recurrent MFMA, B fragments from LDS ----
        f4 acc0 = (f4){0.f, 0.f, 0.f, 0.f}, acc1 = acc0;
#pragma unroll
        for (int kt = 0; kt < 16; ++kt) {
            short8 b0 = *(const short8*)(&whl[kt * 512 + lm * 32 + q * 8]);
            short8 b1 = *(const short8*)(&whl[(16 + kt) * 512 + lm * 32 + q * 8]);
            acc0 = MFMA_BF16(au[kt].v, b0, acc0);
            acc1 = MFMA_BF16(au[kt].v, b1, acc1);
        }

        // ---- intra-wave transpose via LDS (wave-private rows, no barrier) ----
#pragma unroll
        for (int r = 0; r < 4; ++r) {
            int brow = w * 16 + q * 4 + r;
            gb[brow * 36 + lm] = acc0[r];
            gb[brow * 36 + 16 + lm] = acc1[r];
        }
        f4 g0 = *(const f4*)(&gb[be * 36 + u0 * 4]);
        f4 g1 = *(const f4*)(&gb[be * 36 + u0 * 4 + 4]);

        g0 += xv0 + bias0;
        g1 += xv1 + bias1;
        float i1 = sigf(g0.x), f1 = sigf(g0.y), gg1 = tanh_(g0.z), o1 = sigf(g0.w);
        c0r = f1 * c0r + i1 * gg1;
        float h1 = o1 * tanh_(c0r);
        float i2 = sigf(g1.x), fg2 = sigf(g1.y), gg2 = tanh_(g1.z), o2 = sigf(g1.w);
        c1r = fg2 * c1r + i2 * gg2;
        float h2 = o2 * tanh_(c1r);

        // ---- publish h(t), wave-local drain, per-wave flag ----
        u32 hv = (u32)bf16rne(h1) | ((u32)bf16rne(h2) << 16);
        u32* hw = (u32*)(hbuf + (size_t)(t & 1) * 32768 + be * Hsz + j0 + u0);
        __hip_atomic_store(hw, hv, __ATOMIC_RELAXED, __HIP_MEMORY_SCOPE_AGENT);
        asm volatile("s_waitcnt vmcnt(0)" ::: "memory");   // h store at MALL
        if (L == 0)
            __hip_atomic_store(&flag[(size_t)t * 256 + w * 64 + bid], 1,
                               __ATOMIC_RELAXED, __HIP_MEMORY_SCOPE_AGENT);

        // out stores off the protocol's critical path
        float* op = out + ((size_t)be * Ssz + t) * Hsz + j0 + u0;
        op[0] = h1;
        op[1] = h2;
        if (t == Ssz - 1) {
            out[HF_OFF + be * Hsz + j0 + u0] = h1;
            out[HF_OFF + be * Hsz + j0 + u0 + 1] = h2;
            out[CF_OFF + be * Hsz + j0 + u0] = c0r;
            out[CF_OFF + be * Hsz + j0 + u0 + 1] = c1r;
        }
    }
    cbuf[be * Hsz + j0 + u0] = c0r;
    cbuf[be * Hsz + j0 + u0 + 1] = c1r;
}

// ------------------------------------------------------------------
extern "C" void kernel_launch(void* const* d_in, const int* in_sizes, int n_in,
                              void* d_out, int out_size, void* d_ws, size_t ws_size,
                              hipStream_t stream) {
    const float* inputs = (const float*)d_in[0];
    char* W = (char*)d_ws;
    int*  flag = (int*)(W + WS_FLAG);
    float* bias = (float*)(W + WS_BIAS);
    u16*  hbuf = (u16*)(W + WS_HBUF);
    float* cbuf = (float*)(W + WS_CBUF);
    u16*  Wi   = (u16*)(W + WS_WI);
    u16*  Wh   = (u16*)(W + WS_WH);
    float* xch  = (float*)(W + WS_XC);

    PrepArgs a;
    a.h0 = (const float*)d_in[1];
    a.c0 = (const float*)d_in[2];
    for (int g = 0; g < 4; ++g) {
        a.wi[g] = (const float*)d_in[3 + g];
        a.wh[g] = (const float*)d_in[7 + g];
        a.bi[g] = (const float*)d_in[11 + g];
    }
    // dict order at the tail is b_hi, b_hf, b_ho, b_hg -> remap to (i,f,g,o)
    a.bh[0] = (const float*)d_in[15];
    a.bh[1] = (const float*)d_in[16];
    a.bh[2] = (const float*)d_in[18];
    a.bh[3] = (const float*)d_in[17];
    a.Wi = Wi; a.Wh = Wh; a.bias = bias; a.hbuf = hbuf; a.cbuf = cbuf; a.flag = flag;

    lstm_prep<<<(PREP_TOT + 255) / 256, 256, 0, stream>>>(a);

    float* out = (float*)d_out;
    for (int c = 0; c < NCHUNK; ++c) {
        int t0 = c * SCH;
        xproj_gemm<<<dim3(64 * 16), 256, 0, stream>>>(inputs, Wi, xch, t0);
        lstm_scan<<<dim3(SCAN_NB), 256, 0, stream>>>(xch, Wh, bias, hbuf, cbuf, flag, out, t0);
    }
}